// Round 12
// baseline (338.544 us; speedup 1.0000x reference)
//
#include <hip/hip_runtime.h>
#include <hip/hip_bf16.h>

#define N_NODES 50000
#define N_EDGES 800000
#define TOT_E   (N_EDGES + N_NODES)
#define NBUCK   ((N_NODES + 127) / 128)     // 391 buckets of 128 dst nodes
#define BCAP    3072                         // bucket capacity (avg 2048, max ~2300)
#define PART_BLOCKS 256
#define EPB     (N_EDGES / PART_BLOCKS)      // 3125 edges per partition block

typedef __attribute__((ext_vector_type(8))) short short8;
typedef __attribute__((ext_vector_type(4))) float f32x4;

__device__ __forceinline__ unsigned short f2bf(float f) {
  union { float f; unsigned int u; } x; x.f = f;
  unsigned int u = x.u;
  unsigned int r = (u + 0x7FFFu + ((u >> 16) & 1u)) >> 16;  // RNE
  return (unsigned short)r;
}
__device__ __forceinline__ float bflo(unsigned int v) {   // bf16 in low half
  union { unsigned int u; float f; } x; x.u = v << 16; return x.f;
}
__device__ __forceinline__ float bfhi(unsigned int v) {   // bf16 in high half
  union { unsigned int u; float f; } x; x.u = v & 0xffff0000u; return x.f;
}

// ---- init: zero sums/cursors, detect dtype, pre-convert W -> bf16 --------
// Grid = 64 blocks (16384 threads) exactly covers all work items.

__global__ void init_kernel(float* __restrict__ sums1, float* __restrict__ sums2,
                            int* __restrict__ rs, int* __restrict__ cur,
                            const int* __restrict__ ei, int* __restrict__ flag,
                            const float* __restrict__ W1, const float* __restrict__ W2,
                            const float* __restrict__ W3, unsigned short* __restrict__ Wb1,
                            unsigned short* __restrict__ Wb2, unsigned short* __restrict__ Wb3) {
  int i = blockIdx.x * 256 + threadIdx.x;
  if (i < 256) { sums1[i] = 0.f; sums2[i] = 0.f; }
  if (i < NBUCK) cur[i] = i * BCAP;
  if (i == 0) rs[N_NODES] = TOT_E;
  if (i < 16384) Wb1[i] = f2bf(W1[i]);
  if (i < 16384) Wb2[i] = f2bf(W2[i]);
  if (i < 8192)  Wb3[i] = f2bf(W3[i]);
  // int64 detection: odd int32 words of first 64 entries all zero => int64
  if (blockIdx.x == 0 && threadIdx.x < 64) {
    int v = ei[2 * threadIdx.x + 1];
    unsigned long long b = __ballot(v != 0);
    if (threadIdx.x == 0) flag[0] = (b == 0ULL) ? 1 : 0;
  }
}

// ---- partition: bucket edges by dst>>7, LDS-sorted coalesced flush -------

__global__ __launch_bounds__(1024) void part_kernel(const int* __restrict__ ei,
    const int* __restrict__ flag, int* __restrict__ cur, unsigned int* __restrict__ part) {
  __shared__ int hist[NBUCK];
  __shared__ int hist2[NBUCK];
  __shared__ int lexcl[NBUCK];
  __shared__ int gbase[NBUCK];
  __shared__ int wtot[8];
  __shared__ unsigned int sorted[EPB];
  int tid = threadIdx.x;
  int e0 = blockIdx.x * EPB;
  for (int i = tid; i < NBUCK; i += 1024) { hist[i] = 0; hist2[i] = 0; }
  __syncthreads();
  bool i64 = flag[0] != 0;
  // pass 1: bucket histogram
  for (int i = tid; i < EPB; i += 1024) {
    int e = e0 + i;
    int d = i64 ? ei[2 * (N_EDGES + e)] : ei[N_EDGES + e];
    atomicAdd(&hist[d >> 7], 1);
  }
  __syncthreads();
  // exclusive scan of hist -> lexcl (NBUCK <= 512: 8 waves)
  if (tid < 512) {
    int lane = tid & 63, w = tid >> 6;
    int h = (tid < NBUCK) ? hist[tid] : 0;
    int v = h;
#pragma unroll
    for (int off = 1; off < 64; off <<= 1) {
      int u = __shfl_up(v, off);
      if (lane >= off) v += u;
    }
    if (lane == 63) wtot[w] = v;
    if (tid < NBUCK) lexcl[tid] = v - h;
  }
  __syncthreads();
  if (tid < NBUCK) {
    int w = tid >> 6, off = 0;
    for (int k = 0; k < w; k++) off += wtot[k];
    lexcl[tid] += off;
    gbase[tid] = atomicAdd(&cur[tid], hist[tid]);   // reserve global range
  }
  __syncthreads();
  // pass 2: stage edges sorted by bucket in LDS
  for (int i = tid; i < EPB; i += 1024) {
    int e = e0 + i;
    int s, d;
    if (i64) { s = ei[2 * e]; d = ei[2 * (N_EDGES + e)]; }
    else     { s = ei[e];     d = ei[N_EDGES + e]; }
    int b = d >> 7;
    int ls = atomicAdd(&hist2[b], 1);
    sorted[lexcl[b] + ls] = ((unsigned int)d << 16) | (unsigned int)s;
  }
  __syncthreads();
  // flush: consecutive tid -> consecutive slots within bucket (coalesced runs)
  for (int j = tid; j < EPB; j += 1024) {
    unsigned int pk = sorted[j];
    int b = (int)(pk >> 23);                      // (d>>16)>>7
    part[gbase[b] + (j - lexcl[b])] = pk;
  }
}

// ---- finalize: per-bucket CSR (ushort), rs, dinv; bscan folded in --------

__global__ __launch_bounds__(256) void fin_kernel(const unsigned int* __restrict__ part,
    const int* __restrict__ cur, unsigned short* __restrict__ csr,
    int* __restrict__ rs, float* __restrict__ dinv) {
  __shared__ int cnt[128], excl[128], iscan[128];
  __shared__ int redbuf[256];
  __shared__ unsigned short ord[BCAP];
  __shared__ unsigned short cls[BCAP + 128];
  int b = blockIdx.x, tid = threadIdx.x;
  int n0 = b * 128;
  int nn = N_NODES - n0; if (nn > 128) nn = 128;
  int ecnt = cur[b] - b * BCAP; if (ecnt > BCAP) ecnt = BCAP;
  int ebase = b * BCAP;
  // csrbase reduction: sum real counts of buckets < b (+128 self-loops each)
  int partial = 0;
  for (int i = tid; i < b; i += 256) partial += cur[i] - i * BCAP + 128;
  redbuf[tid] = partial;
  if (tid < 128) cnt[tid] = 1;                    // self-loop
  __syncthreads();
  if (tid < 128) redbuf[tid] += redbuf[tid + 128];
  for (int i = tid; i < ecnt; i += 256) {
    int dl = (int)((part[ebase + i] >> 16) & 127u);
    ord[i] = (unsigned short)atomicAdd(&cnt[dl], 1);
  }
  __syncthreads();
  // finish reduction with wave 0
  if (tid < 64) {
    int v = redbuf[tid] + redbuf[tid + 64];
#pragma unroll
    for (int off = 32; off; off >>= 1) v += __shfl_xor(v, off);
    redbuf[0] = v;
  }
  // exclusive scan of cnt[0..128): 2 waves
  if (tid >= 128 && tid < 256) {
    int t2 = tid - 128;
    int lane = t2 & 63;
    int c = cnt[t2], v = c;
#pragma unroll
    for (int off = 1; off < 64; off <<= 1) {
      int u = __shfl_up(v, off);
      if (lane >= off) v += u;
    }
    iscan[t2] = v;
  }
  __syncthreads();
  if (tid < 128)
    excl[tid] = iscan[tid] - cnt[tid] + ((tid >= 64) ? iscan[63] : 0);
  __syncthreads();
  int base = redbuf[0];
  // place self-loops then edges
  if (tid < nn) cls[excl[tid]] = (unsigned short)(n0 + tid);
  __syncthreads();
  for (int i = tid; i < ecnt; i += 256) {
    unsigned int pk = part[ebase + i];
    int dl = (int)((pk >> 16) & 127u);
    cls[excl[dl] + ord[i]] = (unsigned short)(pk & 0xffffu);
  }
  __syncthreads();
  int tot = ecnt + nn;
  for (int j = tid; j < tot; j += 256) csr[base + j] = cls[j];
  if (tid < nn) {
    rs[n0 + tid] = base + excl[tid];
    dinv[n0 + tid] = rsqrtf((float)cnt[tid]);
  }
}

// ---- dense matmul with fused A-side BN/ReLU/bf16 cast --------------------
// BN==0: A is fp32 [N][128] raw (layer 1 input x).
// BN==1: A is bf16-packed dwords [N][64] (prev agg out); apply BN+ReLU.
// W pre-converted to bf16 (Wb). Epilogue folds dinv.

template <int OUT, int BN>
__global__ __launch_bounds__(256) void mm_kernel(const void* __restrict__ Ain,
    const float* __restrict__ sums, const float* __restrict__ g,
    const float* __restrict__ bt, const unsigned short* __restrict__ Wb,
    const float* __restrict__ dinv, unsigned short* __restrict__ Hb) {
  constexpr int K = 128;
  constexpr int LDW = K + 8;
  __shared__ __align__(16) unsigned short Wl[OUT * LDW];
  __shared__ float scs[128], shs[128];
  int tid = threadIdx.x;
  // stage Wb -> Wl via uint4 (8 ush per chunk; 16 chunks per row, row-aligned)
#pragma unroll
  for (int c = tid; c < OUT * K / 8; c += 256) {
    int row = c >> 4, col = (c & 15) * 8;
    uint4 v = *(const uint4*)(Wb + row * K + col);
    *(uint4*)(Wl + row * LDW + col) = v;
  }
  if (BN && tid < 128) {
    const float inv_n = 1.0f / (float)N_NODES;
    float mean = sums[tid] * inv_n;
    float var  = sums[128 + tid] * inv_n - mean * mean;
    float sc = g[tid] * rsqrtf(var + 1e-5f);
    scs[tid] = sc;
    shs[tid] = bt[tid] - mean * sc;
  }
  __syncthreads();

  int lane = tid & 63;
  int wv = tid >> 6;
  int m = lane & 15, q = lane >> 4;
  long n0 = (long)blockIdx.x * 64 + wv * 16;
  long arow = n0 + m; if (arow > N_NODES - 1) arow = N_NODES - 1;

  short8 a[4];
  if (BN) {
    const unsigned int* A32 = (const unsigned int*)Ain;
#pragma unroll
    for (int kb = 0; kb < 4; kb++) {
      uint4 v = *(const uint4*)(A32 + (size_t)arow * 64 + kb * 16 + q * 4);
      unsigned int vv[4] = {v.x, v.y, v.z, v.w};
      short8 t;
#pragma unroll
      for (int j = 0; j < 4; j++) {
        int ch = kb * 32 + q * 8 + j * 2;
        float lo = bflo(vv[j]) * scs[ch] + shs[ch];
        float hi = bfhi(vv[j]) * scs[ch + 1] + shs[ch + 1];
        lo = fmaxf(lo, 0.f); hi = fmaxf(hi, 0.f);
        t[2 * j] = (short)f2bf(lo); t[2 * j + 1] = (short)f2bf(hi);
      }
      a[kb] = t;
    }
  } else {
    const float* Af = (const float*)Ain;
#pragma unroll
    for (int kb = 0; kb < 4; kb++) {
      const float* p = Af + (size_t)arow * 128 + kb * 32 + q * 8;
      float4 v0 = *(const float4*)(p);
      float4 v1 = *(const float4*)(p + 4);
      short8 t;
      t[0] = (short)f2bf(v0.x); t[1] = (short)f2bf(v0.y);
      t[2] = (short)f2bf(v0.z); t[3] = (short)f2bf(v0.w);
      t[4] = (short)f2bf(v1.x); t[5] = (short)f2bf(v1.y);
      t[6] = (short)f2bf(v1.z); t[7] = (short)f2bf(v1.w);
      a[kb] = t;
    }
  }

  f32x4 acc[OUT / 16];
#pragma unroll
  for (int t = 0; t < OUT / 16; t++) acc[t] = (f32x4){0.f, 0.f, 0.f, 0.f};

#pragma unroll
  for (int ot = 0; ot < OUT / 16; ot++) {
    const unsigned short* wrow = Wl + (size_t)(ot * 16 + m) * LDW + q * 8;
    short8 b0 = *(const short8*)(wrow);
    short8 b1 = *(const short8*)(wrow + 32);
    short8 b2 = *(const short8*)(wrow + 64);
    short8 b3 = *(const short8*)(wrow + 96);
    acc[ot] = __builtin_amdgcn_mfma_f32_16x16x32_bf16(a[0], b0, acc[ot], 0, 0, 0);
    acc[ot] = __builtin_amdgcn_mfma_f32_16x16x32_bf16(a[1], b1, acc[ot], 0, 0, 0);
    acc[ot] = __builtin_amdgcn_mfma_f32_16x16x32_bf16(a[2], b2, acc[ot], 0, 0, 0);
    acc[ot] = __builtin_amdgcn_mfma_f32_16x16x32_bf16(a[3], b3, acc[ot], 0, 0, 0);
  }

  float dn[4];
#pragma unroll
  for (int r = 0; r < 4; r++) {
    long n = n0 + q * 4 + r;
    dn[r] = (n < N_NODES) ? dinv[n] : 0.f;
  }
#pragma unroll
  for (int ot = 0; ot < OUT / 16; ot++) {
#pragma unroll
    for (int r = 0; r < 4; r++) {
      long n = n0 + q * 4 + r;            // D: row = quad*4 + reg, col = lane&15
      if (n < N_NODES) Hb[n * OUT + ot * 16 + m] = f2bf(dn[r] * acc[ot][r]);
    }
  }
}

// ---- aggregation: out[i] = dinv[i] * sum_j Hb[s_j] + bias ----------------
// 1 node/wave (wave-uniform beg/end, forced scalar via readfirstlane so loop
// control + csr addresses live in SGPRs). Unmasked 16/8/4/1 unroll.
// launch_bounds(256,4): VGPR cap 128 for deep load pipeline. NO fused stats
// (R6/R10 post-mortems: reduction epilogues trigger spills/serialization).

#define LD128(k) unsigned int v##k = H32[(size_t)e##k * 64 + lane]
#define AC128(k, X, Y) { X += bflo(v##k); Y += bfhi(v##k); }

__global__ __launch_bounds__(256, 4) void agg128_kernel(const unsigned int* __restrict__ H32,
    const int* __restrict__ rs, const unsigned short* __restrict__ csr,
    const float* __restrict__ dinv, const float* __restrict__ bias,
    unsigned int* __restrict__ outb) {
  int lane = threadIdx.x & 63;                  // dword index in row (2 channels)
  int node = blockIdx.x * 4 + (threadIdx.x >> 6);   // wave-uniform; grid exact
  int beg = __builtin_amdgcn_readfirstlane(rs[node]);
  int end = __builtin_amdgcn_readfirstlane(rs[node + 1]);
  float ax0 = 0.f, ay0 = 0.f, ax1 = 0.f, ay1 = 0.f;
  float ax2 = 0.f, ay2 = 0.f, ax3 = 0.f, ay3 = 0.f;
  int j = beg;
  for (; j + 16 <= end; j += 16) {
    int e0 = csr[j],      e1 = csr[j + 1],  e2 = csr[j + 2],  e3 = csr[j + 3];
    int e4 = csr[j + 4],  e5 = csr[j + 5],  e6 = csr[j + 6],  e7 = csr[j + 7];
    int e8 = csr[j + 8],  e9 = csr[j + 9],  e10 = csr[j + 10], e11 = csr[j + 11];
    int e12 = csr[j + 12], e13 = csr[j + 13], e14 = csr[j + 14], e15 = csr[j + 15];
    LD128(0); LD128(1); LD128(2); LD128(3);
    LD128(4); LD128(5); LD128(6); LD128(7);
    LD128(8); LD128(9); LD128(10); LD128(11);
    LD128(12); LD128(13); LD128(14); LD128(15);
    AC128(0, ax0, ay0); AC128(1, ax1, ay1); AC128(2, ax2, ay2); AC128(3, ax3, ay3);
    AC128(4, ax0, ay0); AC128(5, ax1, ay1); AC128(6, ax2, ay2); AC128(7, ax3, ay3);
    AC128(8, ax0, ay0); AC128(9, ax1, ay1); AC128(10, ax2, ay2); AC128(11, ax3, ay3);
    AC128(12, ax0, ay0); AC128(13, ax1, ay1); AC128(14, ax2, ay2); AC128(15, ax3, ay3);
  }
  if (j + 8 <= end) {
    int e0 = csr[j],     e1 = csr[j + 1], e2 = csr[j + 2], e3 = csr[j + 3];
    int e4 = csr[j + 4], e5 = csr[j + 5], e6 = csr[j + 6], e7 = csr[j + 7];
    LD128(0); LD128(1); LD128(2); LD128(3);
    LD128(4); LD128(5); LD128(6); LD128(7);
    AC128(0, ax0, ay0); AC128(1, ax1, ay1); AC128(2, ax2, ay2); AC128(3, ax3, ay3);
    AC128(4, ax0, ay0); AC128(5, ax1, ay1); AC128(6, ax2, ay2); AC128(7, ax3, ay3);
    j += 8;
  }
  if (j + 4 <= end) {
    int e0 = csr[j], e1 = csr[j + 1], e2 = csr[j + 2], e3 = csr[j + 3];
    LD128(0); LD128(1); LD128(2); LD128(3);
    AC128(0, ax0, ay0); AC128(1, ax1, ay1); AC128(2, ax2, ay2); AC128(3, ax3, ay3);
    j += 4;
  }
  for (; j < end; ++j) {
    int e0 = csr[j];
    LD128(0);
    AC128(0, ax0, ay0);
  }
  float di = dinv[node];
  int c = lane * 2;
  float rx = (ax0 + ax1 + ax2 + ax3) * di + bias[c];
  float ry = (ay0 + ay1 + ay2 + ay3) * di + bias[c + 1];
  outb[(size_t)node * 64 + lane] = (unsigned int)f2bf(rx) | ((unsigned int)f2bf(ry) << 16);
}

// 64ch final layer: 2 nodes/wave (32 lanes each), 16/8/4/1, fp32 out

#define LD64(k) unsigned int v##k = H32[(size_t)e##k * 32 + l]

__global__ __launch_bounds__(256, 4) void agg64_kernel(const unsigned int* __restrict__ H32,
    const int* __restrict__ rs, const unsigned short* __restrict__ csr,
    const float* __restrict__ dinv, const float* __restrict__ bias,
    float* __restrict__ out) {
  int l = threadIdx.x & 31;                     // dword index in row
  int node = blockIdx.x * 8 + (threadIdx.x >> 5);   // grid exact
  int beg = rs[node], end = rs[node + 1];
  float ax0 = 0.f, ay0 = 0.f, ax1 = 0.f, ay1 = 0.f;
  float ax2 = 0.f, ay2 = 0.f, ax3 = 0.f, ay3 = 0.f;
  int j = beg;
  for (; j + 16 <= end; j += 16) {
    int e0 = csr[j],      e1 = csr[j + 1],  e2 = csr[j + 2],  e3 = csr[j + 3];
    int e4 = csr[j + 4],  e5 = csr[j + 5],  e6 = csr[j + 6],  e7 = csr[j + 7];
    int e8 = csr[j + 8],  e9 = csr[j + 9],  e10 = csr[j + 10], e11 = csr[j + 11];
    int e12 = csr[j + 12], e13 = csr[j + 13], e14 = csr[j + 14], e15 = csr[j + 15];
    LD64(0); LD64(1); LD64(2); LD64(3);
    LD64(4); LD64(5); LD64(6); LD64(7);
    LD64(8); LD64(9); LD64(10); LD64(11);
    LD64(12); LD64(13); LD64(14); LD64(15);
    AC128(0, ax0, ay0); AC128(1, ax1, ay1); AC128(2, ax2, ay2); AC128(3, ax3, ay3);
    AC128(4, ax0, ay0); AC128(5, ax1, ay1); AC128(6, ax2, ay2); AC128(7, ax3, ay3);
    AC128(8, ax0, ay0); AC128(9, ax1, ay1); AC128(10, ax2, ay2); AC128(11, ax3, ay3);
    AC128(12, ax0, ay0); AC128(13, ax1, ay1); AC128(14, ax2, ay2); AC128(15, ax3, ay3);
  }
  if (j + 8 <= end) {
    int e0 = csr[j],     e1 = csr[j + 1], e2 = csr[j + 2], e3 = csr[j + 3];
    int e4 = csr[j + 4], e5 = csr[j + 5], e6 = csr[j + 6], e7 = csr[j + 7];
    LD64(0); LD64(1); LD64(2); LD64(3);
    LD64(4); LD64(5); LD64(6); LD64(7);
    AC128(0, ax0, ay0); AC128(1, ax1, ay1); AC128(2, ax2, ay2); AC128(3, ax3, ay3);
    AC128(4, ax0, ay0); AC128(5, ax1, ay1); AC128(6, ax2, ay2); AC128(7, ax3, ay3);
    j += 8;
  }
  if (j + 4 <= end) {
    int e0 = csr[j], e1 = csr[j + 1], e2 = csr[j + 2], e3 = csr[j + 3];
    LD64(0); LD64(1); LD64(2); LD64(3);
    AC128(0, ax0, ay0); AC128(1, ax1, ay1); AC128(2, ax2, ay2); AC128(3, ax3, ay3);
    j += 4;
  }
  for (; j < end; ++j) {
    int e0 = csr[j];
    LD64(0);
    AC128(0, ax0, ay0);
  }
  float di = dinv[node];
  int c = l * 2;
  out[(size_t)node * 64 + c]     = (ax0 + ax1 + ax2 + ax3) * di + bias[c];
  out[(size_t)node * 64 + c + 1] = (ay0 + ay1 + ay2 + ay3) * di + bias[c + 1];
}

// ---- BN stats over bf16-packed agg output (uint2 reads) ------------------

__global__ __launch_bounds__(256) void stats_kernel(const uint2* __restrict__ B,
                                                    float* __restrict__ sums) {
  int tid = threadIdx.x;
  int li = tid & 31;                      // uint2 index in row (4 channels)
  int grp = tid >> 5;                     // 8 row-groups per block
  float s0 = 0.f, s1 = 0.f, s2 = 0.f, s3 = 0.f;
  float q0 = 0.f, q1 = 0.f, q2 = 0.f, q3 = 0.f;
  for (int r = blockIdx.x * 8 + grp; r < N_NODES; r += gridDim.x * 8) {
    uint2 v = B[(size_t)r * 32 + li];
    float x0 = bflo(v.x), x1 = bfhi(v.x), x2 = bflo(v.y), x3 = bfhi(v.y);
    s0 += x0; s1 += x1; s2 += x2; s3 += x3;
    q0 += x0 * x0; q1 += x1 * x1; q2 += x2 * x2; q3 += x3 * x3;
  }
  __shared__ float red[256][9];           // +1 pad: bank-conflict-free
  red[tid][0] = s0; red[tid][1] = s1; red[tid][2] = s2; red[tid][3] = s3;
  red[tid][4] = q0; red[tid][5] = q1; red[tid][6] = q2; red[tid][7] = q3;
  __syncthreads();
  if (tid < 32) {
#pragma unroll
    for (int k = 0; k < 8; k++) {
      float v = 0.f;
#pragma unroll
      for (int g2 = 0; g2 < 8; g2++) v += red[g2 * 32 + tid][k];
      if (k < 4) atomicAdd(&sums[tid * 4 + k], v);
      else       atomicAdd(&sums[128 + tid * 4 + (k - 4)], v);
    }
  }
}

// ---- driver --------------------------------------------------------------

extern "C" void kernel_launch(void* const* d_in, const int* in_sizes, int n_in,
                              void* d_out, int out_size, void* d_ws, size_t ws_size,
                              hipStream_t stream) {
  const float* x   = (const float*)d_in[0];
  const int*   ei  = (const int*)d_in[1];
  const float* W1  = (const float*)d_in[2];
  const float* b1  = (const float*)d_in[3];
  const float* W2  = (const float*)d_in[4];
  const float* b2  = (const float*)d_in[5];
  const float* W3  = (const float*)d_in[6];
  const float* b3  = (const float*)d_in[7];
  const float* g1  = (const float*)d_in[8];
  const float* bt1 = (const float*)d_in[9];
  const float* g2  = (const float*)d_in[10];
  const float* bt2 = (const float*)d_in[11];
  float* out = (float*)d_out;

  char* p = (char*)d_ws;
  auto carve = [&](size_t bytes) { char* r = p; p += (bytes + 255) & ~(size_t)255; return r; };
  int*   rs      = (int*)  carve((size_t)(N_NODES + 1) * 4);
  float* dinv    = (float*)carve((size_t)N_NODES * 4);
  int*   cur     = (int*)  carve((size_t)NBUCK * 4);
  unsigned int* part = (unsigned int*)carve((size_t)NBUCK * BCAP * 4);
  unsigned short* csr = (unsigned short*)carve((size_t)(TOT_E + 32) * 2);
  float* sums1   = (float*)carve(256 * 4);
  float* sums2   = (float*)carve(256 * 4);
  int*   flag    = (int*)  carve(256);
  unsigned short* Wb1 = (unsigned short*)carve(16384 * 2);
  unsigned short* Wb2 = (unsigned short*)carve(16384 * 2);
  unsigned short* Wb3 = (unsigned short*)carve(8192 * 2);
  unsigned short* Hb = (unsigned short*)carve((size_t)(N_NODES + 1) * 128 * 2);
  unsigned int*   Bb = (unsigned int*)  carve((size_t)N_NODES * 64 * 4);

  init_kernel<<<64, 256, 0, stream>>>(sums1, sums2, rs, cur, ei, flag,
                                      W1, W2, W3, Wb1, Wb2, Wb3);
  part_kernel<<<PART_BLOCKS, 1024, 0, stream>>>(ei, flag, cur, part);
  fin_kernel<<<NBUCK, 256, 0, stream>>>(part, cur, csr, rs, dinv);

  // layer 1: mm(x) -> agg -> stats
  mm_kernel<128, 0><<<(N_NODES + 63) / 64, 256, 0, stream>>>(x, sums1, g1, bt1, Wb1, dinv, Hb);
  agg128_kernel<<<N_NODES / 4, 256, 0, stream>>>((const unsigned int*)Hb, rs, csr, dinv, b1, Bb);
  stats_kernel<<<512, 256, 0, stream>>>((const uint2*)Bb, sums1);

  // layer 2: mm(BN1(Bb)) -> agg -> stats
  mm_kernel<128, 1><<<(N_NODES + 63) / 64, 256, 0, stream>>>(Bb, sums1, g1, bt1, Wb2, dinv, Hb);
  agg128_kernel<<<N_NODES / 4, 256, 0, stream>>>((const unsigned int*)Hb, rs, csr, dinv, b2, Bb);
  stats_kernel<<<512, 256, 0, stream>>>((const uint2*)Bb, sums2);

  // layer 3: mm(BN2(Bb)) -> agg -> out (fp32)
  mm_kernel<64, 1><<<(N_NODES + 63) / 64, 256, 0, stream>>>(Bb, sums2, g2, bt2, Wb3, dinv, Hb);
  agg64_kernel<<<N_NODES / 8, 256, 0, stream>>>((const unsigned int*)Hb, rs, csr, dinv, b3, out);
}

// Round 13
// 294.789 us; speedup vs baseline: 1.1484x; 1.1484x over previous
//
#include <hip/hip_runtime.h>
#include <hip/hip_bf16.h>

#define N_NODES 50000
#define N_EDGES 800000
#define TOT_E   (N_EDGES + N_NODES)
#define NBUCK   ((N_NODES + 127) / 128)     // 391 buckets of 128 dst nodes
#define BCAP    3072                         // bucket capacity (avg 2048, max ~2300)
#define PART_BLOCKS 256
#define EPB     (N_EDGES / PART_BLOCKS)      // 3125 edges per partition block

typedef __attribute__((ext_vector_type(8))) short short8;
typedef __attribute__((ext_vector_type(4))) float f32x4;

__device__ __forceinline__ unsigned short f2bf(float f) {
  union { float f; unsigned int u; } x; x.f = f;
  unsigned int u = x.u;
  unsigned int r = (u + 0x7FFFu + ((u >> 16) & 1u)) >> 16;  // RNE
  return (unsigned short)r;
}
__device__ __forceinline__ float bflo(unsigned int v) {   // bf16 in low half
  union { unsigned int u; float f; } x; x.u = v << 16; return x.f;
}
__device__ __forceinline__ float bfhi(unsigned int v) {   // bf16 in high half
  union { unsigned int u; float f; } x; x.u = v & 0xffff0000u; return x.f;
}

// ---- init: zero sums/cursors, detect dtype, pre-convert W -> bf16 --------
// Grid = 64 blocks (16384 threads) exactly covers all work items.

__global__ void init_kernel(float* __restrict__ sums1, float* __restrict__ sums2,
                            int* __restrict__ rs, int* __restrict__ cur,
                            const int* __restrict__ ei, int* __restrict__ flag,
                            const float* __restrict__ W1, const float* __restrict__ W2,
                            const float* __restrict__ W3, unsigned short* __restrict__ Wb1,
                            unsigned short* __restrict__ Wb2, unsigned short* __restrict__ Wb3) {
  int i = blockIdx.x * 256 + threadIdx.x;
  if (i < 256) { sums1[i] = 0.f; sums2[i] = 0.f; }
  if (i < NBUCK) cur[i] = i * BCAP;
  if (i == 0) rs[N_NODES] = TOT_E;
  if (i < 16384) Wb1[i] = f2bf(W1[i]);
  if (i < 16384) Wb2[i] = f2bf(W2[i]);
  if (i < 8192)  Wb3[i] = f2bf(W3[i]);
  // int64 detection: odd int32 words of first 64 entries all zero => int64
  if (blockIdx.x == 0 && threadIdx.x < 64) {
    int v = ei[2 * threadIdx.x + 1];
    unsigned long long b = __ballot(v != 0);
    if (threadIdx.x == 0) flag[0] = (b == 0ULL) ? 1 : 0;
  }
}

// ---- partition: bucket edges by dst>>7, LDS-sorted coalesced flush -------

__global__ __launch_bounds__(1024) void part_kernel(const int* __restrict__ ei,
    const int* __restrict__ flag, int* __restrict__ cur, unsigned int* __restrict__ part) {
  __shared__ int hist[NBUCK];
  __shared__ int hist2[NBUCK];
  __shared__ int lexcl[NBUCK];
  __shared__ int gbase[NBUCK];
  __shared__ int wtot[8];
  __shared__ unsigned int sorted[EPB];
  int tid = threadIdx.x;
  int e0 = blockIdx.x * EPB;
  for (int i = tid; i < NBUCK; i += 1024) { hist[i] = 0; hist2[i] = 0; }
  __syncthreads();
  bool i64 = flag[0] != 0;
  // pass 1: bucket histogram
  for (int i = tid; i < EPB; i += 1024) {
    int e = e0 + i;
    int d = i64 ? ei[2 * (N_EDGES + e)] : ei[N_EDGES + e];
    atomicAdd(&hist[d >> 7], 1);
  }
  __syncthreads();
  // exclusive scan of hist -> lexcl (NBUCK <= 512: 8 waves)
  if (tid < 512) {
    int lane = tid & 63, w = tid >> 6;
    int h = (tid < NBUCK) ? hist[tid] : 0;
    int v = h;
#pragma unroll
    for (int off = 1; off < 64; off <<= 1) {
      int u = __shfl_up(v, off);
      if (lane >= off) v += u;
    }
    if (lane == 63) wtot[w] = v;
    if (tid < NBUCK) lexcl[tid] = v - h;
  }
  __syncthreads();
  if (tid < NBUCK) {
    int w = tid >> 6, off = 0;
    for (int k = 0; k < w; k++) off += wtot[k];
    lexcl[tid] += off;
    gbase[tid] = atomicAdd(&cur[tid], hist[tid]);   // reserve global range
  }
  __syncthreads();
  // pass 2: stage edges sorted by bucket in LDS
  for (int i = tid; i < EPB; i += 1024) {
    int e = e0 + i;
    int s, d;
    if (i64) { s = ei[2 * e]; d = ei[2 * (N_EDGES + e)]; }
    else     { s = ei[e];     d = ei[N_EDGES + e]; }
    int b = d >> 7;
    int ls = atomicAdd(&hist2[b], 1);
    sorted[lexcl[b] + ls] = ((unsigned int)d << 16) | (unsigned int)s;
  }
  __syncthreads();
  // flush: consecutive tid -> consecutive slots within bucket (coalesced runs)
  for (int j = tid; j < EPB; j += 1024) {
    unsigned int pk = sorted[j];
    int b = (int)(pk >> 23);                      // (d>>16)>>7
    part[gbase[b] + (j - lexcl[b])] = pk;
  }
}

// ---- finalize: per-bucket CSR (ushort), rs, dinv; bscan folded in --------

__global__ __launch_bounds__(256) void fin_kernel(const unsigned int* __restrict__ part,
    const int* __restrict__ cur, unsigned short* __restrict__ csr,
    int* __restrict__ rs, float* __restrict__ dinv) {
  __shared__ int cnt[128], excl[128], iscan[128];
  __shared__ int redbuf[256];
  __shared__ unsigned short ord[BCAP];
  __shared__ unsigned short cls[BCAP + 128];
  int b = blockIdx.x, tid = threadIdx.x;
  int n0 = b * 128;
  int nn = N_NODES - n0; if (nn > 128) nn = 128;
  int ecnt = cur[b] - b * BCAP; if (ecnt > BCAP) ecnt = BCAP;
  int ebase = b * BCAP;
  // csrbase reduction: sum real counts of buckets < b (+128 self-loops each)
  int partial = 0;
  for (int i = tid; i < b; i += 256) partial += cur[i] - i * BCAP + 128;
  redbuf[tid] = partial;
  if (tid < 128) cnt[tid] = 1;                    // self-loop
  __syncthreads();
  if (tid < 128) redbuf[tid] += redbuf[tid + 128];
  for (int i = tid; i < ecnt; i += 256) {
    int dl = (int)((part[ebase + i] >> 16) & 127u);
    ord[i] = (unsigned short)atomicAdd(&cnt[dl], 1);
  }
  __syncthreads();
  // finish reduction with wave 0
  if (tid < 64) {
    int v = redbuf[tid] + redbuf[tid + 64];
#pragma unroll
    for (int off = 32; off; off >>= 1) v += __shfl_xor(v, off);
    redbuf[0] = v;
  }
  // exclusive scan of cnt[0..128): 2 waves
  if (tid >= 128 && tid < 256) {
    int t2 = tid - 128;
    int lane = t2 & 63;
    int c = cnt[t2], v = c;
#pragma unroll
    for (int off = 1; off < 64; off <<= 1) {
      int u = __shfl_up(v, off);
      if (lane >= off) v += u;
    }
    iscan[t2] = v;
  }
  __syncthreads();
  if (tid < 128)
    excl[tid] = iscan[tid] - cnt[tid] + ((tid >= 64) ? iscan[63] : 0);
  __syncthreads();
  int base = redbuf[0];
  // place self-loops then edges
  if (tid < nn) cls[excl[tid]] = (unsigned short)(n0 + tid);
  __syncthreads();
  for (int i = tid; i < ecnt; i += 256) {
    unsigned int pk = part[ebase + i];
    int dl = (int)((pk >> 16) & 127u);
    cls[excl[dl] + ord[i]] = (unsigned short)(pk & 0xffffu);
  }
  __syncthreads();
  int tot = ecnt + nn;
  for (int j = tid; j < tot; j += 256) csr[base + j] = cls[j];
  if (tid < nn) {
    rs[n0 + tid] = base + excl[tid];
    dinv[n0 + tid] = rsqrtf((float)cnt[tid]);
  }
}

// ---- dense matmul with fused A-side BN/ReLU/bf16 cast --------------------
// BN==0: A is fp32 [N][128] raw (layer 1 input x).
// BN==1: A is bf16-packed dwords [N][64] (prev agg out); apply BN+ReLU.
// W pre-converted to bf16 (Wb). Epilogue folds dinv.

template <int OUT, int BN>
__global__ __launch_bounds__(256) void mm_kernel(const void* __restrict__ Ain,
    const float* __restrict__ sums, const float* __restrict__ g,
    const float* __restrict__ bt, const unsigned short* __restrict__ Wb,
    const float* __restrict__ dinv, unsigned short* __restrict__ Hb) {
  constexpr int K = 128;
  constexpr int LDW = K + 8;
  __shared__ __align__(16) unsigned short Wl[OUT * LDW];
  __shared__ float scs[128], shs[128];
  int tid = threadIdx.x;
  // stage Wb -> Wl via uint4 (8 ush per chunk; 16 chunks per row, row-aligned)
#pragma unroll
  for (int c = tid; c < OUT * K / 8; c += 256) {
    int row = c >> 4, col = (c & 15) * 8;
    uint4 v = *(const uint4*)(Wb + row * K + col);
    *(uint4*)(Wl + row * LDW + col) = v;
  }
  if (BN && tid < 128) {
    const float inv_n = 1.0f / (float)N_NODES;
    float mean = sums[tid] * inv_n;
    float var  = sums[128 + tid] * inv_n - mean * mean;
    float sc = g[tid] * rsqrtf(var + 1e-5f);
    scs[tid] = sc;
    shs[tid] = bt[tid] - mean * sc;
  }
  __syncthreads();

  int lane = tid & 63;
  int wv = tid >> 6;
  int m = lane & 15, q = lane >> 4;
  long n0 = (long)blockIdx.x * 64 + wv * 16;
  long arow = n0 + m; if (arow > N_NODES - 1) arow = N_NODES - 1;

  short8 a[4];
  if (BN) {
    const unsigned int* A32 = (const unsigned int*)Ain;
#pragma unroll
    for (int kb = 0; kb < 4; kb++) {
      uint4 v = *(const uint4*)(A32 + (size_t)arow * 64 + kb * 16 + q * 4);
      unsigned int vv[4] = {v.x, v.y, v.z, v.w};
      short8 t;
#pragma unroll
      for (int j = 0; j < 4; j++) {
        int ch = kb * 32 + q * 8 + j * 2;
        float lo = bflo(vv[j]) * scs[ch] + shs[ch];
        float hi = bfhi(vv[j]) * scs[ch + 1] + shs[ch + 1];
        lo = fmaxf(lo, 0.f); hi = fmaxf(hi, 0.f);
        t[2 * j] = (short)f2bf(lo); t[2 * j + 1] = (short)f2bf(hi);
      }
      a[kb] = t;
    }
  } else {
    const float* Af = (const float*)Ain;
#pragma unroll
    for (int kb = 0; kb < 4; kb++) {
      const float* p = Af + (size_t)arow * 128 + kb * 32 + q * 8;
      float4 v0 = *(const float4*)(p);
      float4 v1 = *(const float4*)(p + 4);
      short8 t;
      t[0] = (short)f2bf(v0.x); t[1] = (short)f2bf(v0.y);
      t[2] = (short)f2bf(v0.z); t[3] = (short)f2bf(v0.w);
      t[4] = (short)f2bf(v1.x); t[5] = (short)f2bf(v1.y);
      t[6] = (short)f2bf(v1.z); t[7] = (short)f2bf(v1.w);
      a[kb] = t;
    }
  }

  f32x4 acc[OUT / 16];
#pragma unroll
  for (int t = 0; t < OUT / 16; t++) acc[t] = (f32x4){0.f, 0.f, 0.f, 0.f};

#pragma unroll
  for (int ot = 0; ot < OUT / 16; ot++) {
    const unsigned short* wrow = Wl + (size_t)(ot * 16 + m) * LDW + q * 8;
    short8 b0 = *(const short8*)(wrow);
    short8 b1 = *(const short8*)(wrow + 32);
    short8 b2 = *(const short8*)(wrow + 64);
    short8 b3 = *(const short8*)(wrow + 96);
    acc[ot] = __builtin_amdgcn_mfma_f32_16x16x32_bf16(a[0], b0, acc[ot], 0, 0, 0);
    acc[ot] = __builtin_amdgcn_mfma_f32_16x16x32_bf16(a[1], b1, acc[ot], 0, 0, 0);
    acc[ot] = __builtin_amdgcn_mfma_f32_16x16x32_bf16(a[2], b2, acc[ot], 0, 0, 0);
    acc[ot] = __builtin_amdgcn_mfma_f32_16x16x32_bf16(a[3], b3, acc[ot], 0, 0, 0);
  }

  float dn[4];
#pragma unroll
  for (int r = 0; r < 4; r++) {
    long n = n0 + q * 4 + r;
    dn[r] = (n < N_NODES) ? dinv[n] : 0.f;
  }
#pragma unroll
  for (int ot = 0; ot < OUT / 16; ot++) {
#pragma unroll
    for (int r = 0; r < 4; r++) {
      long n = n0 + q * 4 + r;            // D: row = quad*4 + reg, col = lane&15
      if (n < N_NODES) Hb[n * OUT + ot * 16 + m] = f2bf(dn[r] * acc[ot][r]);
    }
  }
}

// ---- aggregation: out[i] = dinv[i] * sum_j Hb[s_j] + bias ----------------
// 1 node/wave (wave-uniform beg/end, forced scalar via readfirstlane so loop
// control + csr addresses live in SGPRs). Unmasked 16/8/4/1 unroll.
// launch_bounds(256,4): VGPR cap 128 for deep load pipeline. NO fused stats
// (R6/R10/R12 post-mortems: reduction epilogues / persistent accumulators
// trigger spills or register-starved serialization).

#define LD128(k) unsigned int v##k = H32[(size_t)e##k * 64 + lane]
#define AC128(k, X, Y) { X += bflo(v##k); Y += bfhi(v##k); }

__global__ __launch_bounds__(256, 4) void agg128_kernel(const unsigned int* __restrict__ H32,
    const int* __restrict__ rs, const unsigned short* __restrict__ csr,
    const float* __restrict__ dinv, const float* __restrict__ bias,
    unsigned int* __restrict__ outb) {
  int lane = threadIdx.x & 63;                  // dword index in row (2 channels)
  int node = blockIdx.x * 4 + (threadIdx.x >> 6);   // wave-uniform; grid exact
  int beg = __builtin_amdgcn_readfirstlane(rs[node]);
  int end = __builtin_amdgcn_readfirstlane(rs[node + 1]);
  float ax0 = 0.f, ay0 = 0.f, ax1 = 0.f, ay1 = 0.f;
  float ax2 = 0.f, ay2 = 0.f, ax3 = 0.f, ay3 = 0.f;
  int j = beg;
  for (; j + 16 <= end; j += 16) {
    int e0 = csr[j],      e1 = csr[j + 1],  e2 = csr[j + 2],  e3 = csr[j + 3];
    int e4 = csr[j + 4],  e5 = csr[j + 5],  e6 = csr[j + 6],  e7 = csr[j + 7];
    int e8 = csr[j + 8],  e9 = csr[j + 9],  e10 = csr[j + 10], e11 = csr[j + 11];
    int e12 = csr[j + 12], e13 = csr[j + 13], e14 = csr[j + 14], e15 = csr[j + 15];
    LD128(0); LD128(1); LD128(2); LD128(3);
    LD128(4); LD128(5); LD128(6); LD128(7);
    LD128(8); LD128(9); LD128(10); LD128(11);
    LD128(12); LD128(13); LD128(14); LD128(15);
    AC128(0, ax0, ay0); AC128(1, ax1, ay1); AC128(2, ax2, ay2); AC128(3, ax3, ay3);
    AC128(4, ax0, ay0); AC128(5, ax1, ay1); AC128(6, ax2, ay2); AC128(7, ax3, ay3);
    AC128(8, ax0, ay0); AC128(9, ax1, ay1); AC128(10, ax2, ay2); AC128(11, ax3, ay3);
    AC128(12, ax0, ay0); AC128(13, ax1, ay1); AC128(14, ax2, ay2); AC128(15, ax3, ay3);
  }
  if (j + 8 <= end) {
    int e0 = csr[j],     e1 = csr[j + 1], e2 = csr[j + 2], e3 = csr[j + 3];
    int e4 = csr[j + 4], e5 = csr[j + 5], e6 = csr[j + 6], e7 = csr[j + 7];
    LD128(0); LD128(1); LD128(2); LD128(3);
    LD128(4); LD128(5); LD128(6); LD128(7);
    AC128(0, ax0, ay0); AC128(1, ax1, ay1); AC128(2, ax2, ay2); AC128(3, ax3, ay3);
    AC128(4, ax0, ay0); AC128(5, ax1, ay1); AC128(6, ax2, ay2); AC128(7, ax3, ay3);
    j += 8;
  }
  if (j + 4 <= end) {
    int e0 = csr[j], e1 = csr[j + 1], e2 = csr[j + 2], e3 = csr[j + 3];
    LD128(0); LD128(1); LD128(2); LD128(3);
    AC128(0, ax0, ay0); AC128(1, ax1, ay1); AC128(2, ax2, ay2); AC128(3, ax3, ay3);
    j += 4;
  }
  for (; j < end; ++j) {
    int e0 = csr[j];
    LD128(0);
    AC128(0, ax0, ay0);
  }
  float di = dinv[node];
  int c = lane * 2;
  float rx = (ax0 + ax1 + ax2 + ax3) * di + bias[c];
  float ry = (ay0 + ay1 + ay2 + ay3) * di + bias[c + 1];
  outb[(size_t)node * 64 + lane] = (unsigned int)f2bf(rx) | ((unsigned int)f2bf(ry) << 16);
}

// 64ch final layer: 2 nodes/wave (32 lanes each), 16/8/4/1, fp32 out

#define LD64(k) unsigned int v##k = H32[(size_t)e##k * 32 + l]

__global__ __launch_bounds__(256, 4) void agg64_kernel(const unsigned int* __restrict__ H32,
    const int* __restrict__ rs, const unsigned short* __restrict__ csr,
    const float* __restrict__ dinv, const float* __restrict__ bias,
    float* __restrict__ out) {
  int l = threadIdx.x & 31;                     // dword index in row
  int node = blockIdx.x * 8 + (threadIdx.x >> 5);   // grid exact
  int beg = rs[node], end = rs[node + 1];
  float ax0 = 0.f, ay0 = 0.f, ax1 = 0.f, ay1 = 0.f;
  float ax2 = 0.f, ay2 = 0.f, ax3 = 0.f, ay3 = 0.f;
  int j = beg;
  for (; j + 16 <= end; j += 16) {
    int e0 = csr[j],      e1 = csr[j + 1],  e2 = csr[j + 2],  e3 = csr[j + 3];
    int e4 = csr[j + 4],  e5 = csr[j + 5],  e6 = csr[j + 6],  e7 = csr[j + 7];
    int e8 = csr[j + 8],  e9 = csr[j + 9],  e10 = csr[j + 10], e11 = csr[j + 11];
    int e12 = csr[j + 12], e13 = csr[j + 13], e14 = csr[j + 14], e15 = csr[j + 15];
    LD64(0); LD64(1); LD64(2); LD64(3);
    LD64(4); LD64(5); LD64(6); LD64(7);
    LD64(8); LD64(9); LD64(10); LD64(11);
    LD64(12); LD64(13); LD64(14); LD64(15);
    AC128(0, ax0, ay0); AC128(1, ax1, ay1); AC128(2, ax2, ay2); AC128(3, ax3, ay3);
    AC128(4, ax0, ay0); AC128(5, ax1, ay1); AC128(6, ax2, ay2); AC128(7, ax3, ay3);
    AC128(8, ax0, ay0); AC128(9, ax1, ay1); AC128(10, ax2, ay2); AC128(11, ax3, ay3);
    AC128(12, ax0, ay0); AC128(13, ax1, ay1); AC128(14, ax2, ay2); AC128(15, ax3, ay3);
  }
  if (j + 8 <= end) {
    int e0 = csr[j],     e1 = csr[j + 1], e2 = csr[j + 2], e3 = csr[j + 3];
    int e4 = csr[j + 4], e5 = csr[j + 5], e6 = csr[j + 6], e7 = csr[j + 7];
    LD64(0); LD64(1); LD64(2); LD64(3);
    LD64(4); LD64(5); LD64(6); LD64(7);
    AC128(0, ax0, ay0); AC128(1, ax1, ay1); AC128(2, ax2, ay2); AC128(3, ax3, ay3);
    AC128(4, ax0, ay0); AC128(5, ax1, ay1); AC128(6, ax2, ay2); AC128(7, ax3, ay3);
    j += 8;
  }
  if (j + 4 <= end) {
    int e0 = csr[j], e1 = csr[j + 1], e2 = csr[j + 2], e3 = csr[j + 3];
    LD64(0); LD64(1); LD64(2); LD64(3);
    AC128(0, ax0, ay0); AC128(1, ax1, ay1); AC128(2, ax2, ay2); AC128(3, ax3, ay3);
    j += 4;
  }
  for (; j < end; ++j) {
    int e0 = csr[j];
    LD64(0);
    AC128(0, ax0, ay0);
  }
  float di = dinv[node];
  int c = l * 2;
  out[(size_t)node * 64 + c]     = (ax0 + ax1 + ax2 + ax3) * di + bias[c];
  out[(size_t)node * 64 + c + 1] = (ay0 + ay1 + ay2 + ay3) * di + bias[c + 1];
}

// ---- BN stats over bf16-packed agg output (R11 form — proven fast) -------

__global__ __launch_bounds__(256) void stats_kernel(const unsigned int* __restrict__ B32,
                                                    float* __restrict__ sums) {
  __shared__ float lsx[256], lsy[256], l2x[256], l2y[256];
  int tid = threadIdx.x;
  int d = tid & 63, grp = tid >> 6;
  float sx = 0.f, sy = 0.f, qx = 0.f, qy = 0.f;
  for (int r = blockIdx.x * 4 + grp; r < N_NODES; r += gridDim.x * 4) {
    unsigned int v = B32[(size_t)r * 64 + d];
    float x = bflo(v), y = bfhi(v);
    sx += x; sy += y; qx += x * x; qy += y * y;
  }
  lsx[tid] = sx; lsy[tid] = sy; l2x[tid] = qx; l2y[tid] = qy;
  __syncthreads();
  if (tid < 64) {
    float ax = lsx[tid] + lsx[64 + tid] + lsx[128 + tid] + lsx[192 + tid];
    float ay = lsy[tid] + lsy[64 + tid] + lsy[128 + tid] + lsy[192 + tid];
    float bx = l2x[tid] + l2x[64 + tid] + l2x[128 + tid] + l2x[192 + tid];
    float by = l2y[tid] + l2y[64 + tid] + l2y[128 + tid] + l2y[192 + tid];
    atomicAdd(&sums[2 * tid], ax);
    atomicAdd(&sums[2 * tid + 1], ay);
    atomicAdd(&sums[128 + 2 * tid], bx);
    atomicAdd(&sums[128 + 2 * tid + 1], by);
  }
}

// ---- driver --------------------------------------------------------------

extern "C" void kernel_launch(void* const* d_in, const int* in_sizes, int n_in,
                              void* d_out, int out_size, void* d_ws, size_t ws_size,
                              hipStream_t stream) {
  const float* x   = (const float*)d_in[0];
  const int*   ei  = (const int*)d_in[1];
  const float* W1  = (const float*)d_in[2];
  const float* b1  = (const float*)d_in[3];
  const float* W2  = (const float*)d_in[4];
  const float* b2  = (const float*)d_in[5];
  const float* W3  = (const float*)d_in[6];
  const float* b3  = (const float*)d_in[7];
  const float* g1  = (const float*)d_in[8];
  const float* bt1 = (const float*)d_in[9];
  const float* g2  = (const float*)d_in[10];
  const float* bt2 = (const float*)d_in[11];
  float* out = (float*)d_out;

  char* p = (char*)d_ws;
  auto carve = [&](size_t bytes) { char* r = p; p += (bytes + 255) & ~(size_t)255; return r; };
  int*   rs      = (int*)  carve((size_t)(N_NODES + 1) * 4);
  float* dinv    = (float*)carve((size_t)N_NODES * 4);
  int*   cur     = (int*)  carve((size_t)NBUCK * 4);
  unsigned int* part = (unsigned int*)carve((size_t)NBUCK * BCAP * 4);
  unsigned short* csr = (unsigned short*)carve((size_t)(TOT_E + 32) * 2);
  float* sums1   = (float*)carve(256 * 4);
  float* sums2   = (float*)carve(256 * 4);
  int*   flag    = (int*)  carve(256);
  unsigned short* Wb1 = (unsigned short*)carve(16384 * 2);
  unsigned short* Wb2 = (unsigned short*)carve(16384 * 2);
  unsigned short* Wb3 = (unsigned short*)carve(8192 * 2);
  unsigned short* Hb = (unsigned short*)carve((size_t)(N_NODES + 1) * 128 * 2);
  unsigned int*   Bb = (unsigned int*)  carve((size_t)N_NODES * 64 * 4);

  init_kernel<<<64, 256, 0, stream>>>(sums1, sums2, rs, cur, ei, flag,
                                      W1, W2, W3, Wb1, Wb2, Wb3);
  part_kernel<<<PART_BLOCKS, 1024, 0, stream>>>(ei, flag, cur, part);
  fin_kernel<<<NBUCK, 256, 0, stream>>>(part, cur, csr, rs, dinv);

  // layer 1: mm(x) -> agg -> stats
  mm_kernel<128, 0><<<(N_NODES + 63) / 64, 256, 0, stream>>>(x, sums1, g1, bt1, Wb1, dinv, Hb);
  agg128_kernel<<<N_NODES / 4, 256, 0, stream>>>((const unsigned int*)Hb, rs, csr, dinv, b1, Bb);
  stats_kernel<<<512, 256, 0, stream>>>(Bb, sums1);

  // layer 2: mm(BN1(Bb)) -> agg -> stats
  mm_kernel<128, 1><<<(N_NODES + 63) / 64, 256, 0, stream>>>(Bb, sums1, g1, bt1, Wb2, dinv, Hb);
  agg128_kernel<<<N_NODES / 4, 256, 0, stream>>>((const unsigned int*)Hb, rs, csr, dinv, b2, Bb);
  stats_kernel<<<512, 256, 0, stream>>>(Bb, sums2);

  // layer 3: mm(BN2(Bb)) -> agg -> out (fp32)
  mm_kernel<64, 1><<<(N_NODES + 63) / 64, 256, 0, stream>>>(Bb, sums2, g2, bt2, Wb3, dinv, Hb);
  agg64_kernel<<<N_NODES / 8, 256, 0, stream>>>((const unsigned int*)Hb, rs, csr, dinv, b3, out);
}